// Round 5
// baseline (1002.171 us; speedup 1.0000x reference)
//
#include <hip/hip_runtime.h>
#include <hip/hip_bf16.h>

#define TT 6
#define NN 50000
#define EE 800000
#define FF 32
#define HH 64
#define OO 16

#define NB 256        // dst buckets
#define DPB 196       // dsts per bucket (256*196 = 50176 >= 50000)
#define CHUNK 4096    // edges per block in scatter
#define CAP 4096      // slab capacity per (t,bucket): mean 3125, sd 56 -> 17 sigma
#define ASTR 33       // aggf feature stride (pad 32->33: bank = (d+f)%32)

#define WFRAG_N 19456  // 38 slots * 512 bf16 fragment-packed weights
// wbias layout: [0..63] cz, [64..127] cr, [128..191] ch, [192..207] out_b

typedef unsigned short ushort_t;
typedef unsigned char uchar_t;
typedef short short8 __attribute__((ext_vector_type(8)));   // 8 bf16 (4 VGPRs)
typedef float f32x4 __attribute__((ext_vector_type(4)));

__device__ __forceinline__ float ubf(ushort_t v){ return __uint_as_float(((unsigned)v) << 16); }
__device__ __forceinline__ ushort_t f2b(float f){
  unsigned u = __float_as_uint(f);
  return (ushort_t)((u + 0x7FFFu + ((u >> 16) & 1u)) >> 16);
}
__device__ __forceinline__ float lo16f(unsigned u){ return __uint_as_float(u << 16); }
__device__ __forceinline__ float hi16f(unsigned u){ return __uint_as_float(u & 0xFFFF0000u); }

// hardware LDS float atomic (ds_add_f32). Plain atomicAdd(float*) on LDS lowers
// to a CAS retry loop under default flags (v7 post-mortem: 820us, VALUBusy 1.5%,
// 0 bank conflicts -> pure ds_cmpst round-trips). Shared-aperture generic
// pointers have zero low-32 aperture bits on gfx9+, so truncation = LDS offset.
__device__ __forceinline__ void lds_fadd(float* p, float v){
  asm volatile("ds_add_f32 %0, %1" :: "v"((unsigned)(size_t)p), "v"(v) : "memory");
}

// ---------------- fused prep: wfrag (direct from raw weights) + biases + bcur zero
__global__ void prepall_kernel(const float* __restrict__ Wz,const float* __restrict__ bz,
                               const float* __restrict__ Wr,const float* __restrict__ br,
                               const float* __restrict__ Wh,const float* __restrict__ bh,
                               const float* __restrict__ Lz,const float* __restrict__ Lzb,
                               const float* __restrict__ Lr,const float* __restrict__ Lrb,
                               const float* __restrict__ Lh,const float* __restrict__ Lhb,
                               const float* __restrict__ oW,const float* __restrict__ ob,
                               short* __restrict__ wfrag, float* __restrict__ wbias,
                               int* __restrict__ bcur){
  int bid = blockIdx.x, tid = threadIdx.x;
  if (bid < 76){
    int idx = bid*256 + tid;   // 0..19455
    int slot = idx >> 9, lane = (idx >> 3) & 63, j = idx & 7;
    int q = lane >> 4, l15 = lane & 15;
    float val;
    if (slot < 36){
      int g, kc, ncol;
      if (slot < 24){ int nt = slot/3; kc = slot - nt*3; ncol = nt*16 + l15;
                      g = (ncol < 64) ? 0 : 1; ncol &= 63; }
      else          { int s2 = slot-24; int nt = s2/3; kc = s2 - nt*3;
                      ncol = nt*16 + l15; g = 2; }
      const float* W = (g==0)?Wz:((g==1)?Wr:Wh);     // [32][64]
      const float* L = (g==0)?Lz:((g==1)?Lr:Lh);     // [128][64]
      int k = kc*32 + q*8 + j;                        // 0..95
      if (k < 32){                                    // fused W@L[:64]
        float s = 0.f;
        for (int m = 0; m < 64; m++) s += W[k*64+m] * L[m*64+ncol];
        val = s;
      } else val = L[(32+k)*64 + ncol];               // L rows 64..127
    } else {
      int kc = slot - 36;
      int k = kc*32 + q*8 + j;                        // 0..63
      val = oW[k*16 + l15];
    }
    wfrag[idx] = (short)f2b(val);
  } else {
    if (tid < 192){
      int g = tid >> 6, j = tid & 63;
      const float* L  = (g==0)?Lz:((g==1)?Lr:Lh);
      const float* bb = (g==0)?bz:((g==1)?br:bh);
      const float* Lb = (g==0)?Lzb:((g==1)?Lrb:Lhb);
      float s = Lb[j];
      for (int m = 0; m < 64; m++) s += bb[m] * L[m*64+j];
      wbias[tid] = s;
    } else if (tid < 208){
      wbias[tid] = ob[tid-192];
    }
    for (int i = tid; i < 1536; i += 256) bcur[i] = 0;
  }
}

// ---------------- scatter: LDS counting-sort by bucket -> coalesced slab writes --
__global__ __launch_bounds__(256) void scatter_kernel(const int* __restrict__ ei,
                                                      int* __restrict__ bcur,
                                                      ushort_t* __restrict__ ssrc16,
                                                      uchar_t* __restrict__ sdst8){
  int t = blockIdx.y;
  __shared__ int cnt[NB];
  __shared__ int lstart[NB];
  __shared__ int gbase[NB];
  __shared__ int wsum[4];
  __shared__ ushort_t spay[CHUNK];
  __shared__ uchar_t  sdlo[CHUNK];
  __shared__ uchar_t  sbk[CHUNK];
  int tid = threadIdx.x;
  cnt[tid] = 0;
  __syncthreads();
  int e0 = blockIdx.x*CHUNK;
  const int* srcs = ei + t*2*EE;
  const int* dsts = ei + t*2*EE + EE;
  int pk[CHUNK/256];
  int ps[CHUNK/256];
  int pd[CHUNK/256];
  #pragma unroll
  for (int i = 0; i < CHUNK/256; i++){
    int e = e0 + i*256 + tid;
    if (e < EE){
      int s = srcs[e], d = dsts[e];
      int b = d / DPB;
      int lr = atomicAdd(&cnt[b], 1);
      pk[i] = (b << 12) | lr;
      ps[i] = s;
      pd[i] = d - b*DPB;
    } else pk[i] = -1;
  }
  __syncthreads();
  {
    int v = cnt[tid];
    int lane = tid & 63, wid = tid >> 6;
    int x = v;
    #pragma unroll
    for (int o = 1; o < 64; o <<= 1){
      int y = __shfl_up(x, o, 64);
      if (lane >= o) x += y;
    }
    if (lane == 63) wsum[wid] = x;
    __syncthreads();
    if (tid == 0){
      int s = 0;
      #pragma unroll
      for (int w = 0; w < 4; w++){ int tmp = wsum[w]; wsum[w] = s; s += tmp; }
    }
    __syncthreads();
    lstart[tid] = x - v + wsum[wid];
    gbase[tid] = (v > 0) ? atomicAdd(&bcur[t*NB + tid], v) : 0;
  }
  __syncthreads();
  #pragma unroll
  for (int i = 0; i < CHUNK/256; i++){
    if (pk[i] >= 0){
      int b = pk[i] >> 12, lr = pk[i] & 4095;
      int pos = lstart[b] + lr;
      spay[pos] = (ushort_t)ps[i];
      sdlo[pos] = (uchar_t)pd[i];
      sbk[pos]  = (uchar_t)b;
    }
  }
  __syncthreads();
  int nE = EE - e0; if (nE > CHUNK) nE = CHUNK;
  for (int i = tid; i < nE; i += 256){
    int b = sbk[i];
    int gpos = gbase[b] + (i - lstart[b]);
    if (gpos < CAP){
      size_t sb = (size_t)(t*NB + b)*CAP + gpos;
      ssrc16[sb] = spay[i];
      sdst8[sb]  = sdlo[i];
    }
  }
}

// ---------------- per-bucket degree -> dinv (reads u8 slab only) ----------------
__global__ __launch_bounds__(256) void degdinv_kernel(const uchar_t* __restrict__ sdst8,
                                                      const int* __restrict__ bcur,
                                                      float* __restrict__ dinv){
  int b = blockIdx.x, t = blockIdx.y, tid = threadIdx.x;
  __shared__ int cnt[DPB];
  for (int i = tid; i < DPB; i += 256) cnt[i] = 0;
  __syncthreads();
  int ecnt = bcur[t*NB + b]; if (ecnt > CAP) ecnt = CAP;
  const uchar_t* dp = sdst8 + (size_t)(t*NB + b)*CAP;
  for (int i = tid; i < ecnt; i += 256)
    atomicAdd(&cnt[dp[i]], 1);
  __syncthreads();
  for (int i = tid; i < DPB; i += 256){
    int n = b*DPB + i;
    if (n < NN) dinv[t*NN + n] = rsqrtf((float)(cnt[i] + 1));  // +1 self loop
  }
}

// ---------------- convert + pre-scale: xbs[t][n][f] = bf16(dinv[t][n] * x[t][n][f])
__global__ void cvtscale_kernel(const float4* __restrict__ x4,
                                const float* __restrict__ dinv,
                                ushort4* __restrict__ xb4){
  int i = blockIdx.x*256 + threadIdx.x;     // float4 index, 2,400,000 total
  if (i < TT*NN*8){
    float dn = dinv[i >> 3];
    float4 v = x4[i];
    ushort4 o;
    o.x = f2b(v.x*dn); o.y = f2b(v.y*dn); o.z = f2b(v.z*dn); o.w = f2b(v.w*dn);
    xb4[i] = o;
  }
}

// ---------------- bucket gather v8: edge-centric + HW ds_add_f32 ---------------
// v7 structure (validated correct) with the one broken piece swapped: LDS float
// accumulation now uses raw ds_add_f32 instead of atomicAdd's CAS loop.
__global__ __launch_bounds__(256) void gatherb_kernel(const ushort_t* __restrict__ xbs,
                                                      const ushort_t* __restrict__ ssrc16,
                                                      const uchar_t* __restrict__ sdst8,
                                                      const int* __restrict__ bcur,
                                                      const float* __restrict__ dinv,
                                                      ushort_t* __restrict__ aggb){
  int l = blockIdx.x;
  int wk = ((l & 7) * 192) + (l >> 3);
  int t = wk >> 8;
  int b = wk & 255;
  int tid = threadIdx.x;
  __shared__ float aggf[DPB*ASTR];    // 25.9 KB f32 accumulator
  for (int i = tid; i < DPB*ASTR; i += 256) aggf[i] = 0.f;
  __syncthreads();
  int ecnt = bcur[t*NB + b]; if (ecnt > CAP) ecnt = CAP;
  size_t slab = (size_t)(t*NB + b)*CAP;
  const ushort_t* sp = ssrc16 + slab;
  const uchar_t*  dp = sdst8 + slab;
  const uint4* xb4 = (const uint4*)xbs + (size_t)t*NN*4;   // row = 4 x uint4
  int fp = tid & 3, eg = tid >> 2;    // 64 edge-groups per block
  for (int e = eg; e < ecnt; e += 64*4){
    int ss[4], dd[4]; bool vv[4];
    #pragma unroll
    for (int k = 0; k < 4; k++){
      int ek = e + 64*k;
      vv[k] = (ek < ecnt);
      int idx = vv[k] ? ek : 0;
      ss[k] = (int)sp[idx];
      dd[k] = (int)dp[idx];
    }
    uint4 rr[4];
    #pragma unroll
    for (int k = 0; k < 4; k++)
      rr[k] = xb4[(size_t)ss[k]*4 + fp];
    #pragma unroll
    for (int k = 0; k < 4; k++){
      if (!vv[k]){ rr[k].x = 0u; rr[k].y = 0u; rr[k].z = 0u; rr[k].w = 0u; }
      float* ap = &aggf[dd[k]*ASTR + fp*8];
      lds_fadd(ap+0, lo16f(rr[k].x));
      lds_fadd(ap+1, hi16f(rr[k].x));
      lds_fadd(ap+2, lo16f(rr[k].y));
      lds_fadd(ap+3, hi16f(rr[k].y));
      lds_fadd(ap+4, lo16f(rr[k].z));
      lds_fadd(ap+5, hi16f(rr[k].z));
      lds_fadd(ap+6, lo16f(rr[k].w));
      lds_fadd(ap+7, hi16f(rr[k].w));
    }
  }
  asm volatile("s_waitcnt lgkmcnt(0)" ::: "memory");  // drain asm DS ops
  __syncthreads();
  // writeback: (d, quad) pairs; self term + dinv scale; 64B coalesced stores
  const float* dv = dinv + (size_t)t*NN;
  uint4* agg4 = (uint4*)aggb + (size_t)t*NN*4;
  for (int i = tid; i < DPB*4; i += 256){
    int d = i >> 2, fq = i & 3;
    int n = b*DPB + d;
    if (n < NN){
      float dn = dv[n];
      uint4 sv = xb4[(size_t)n*4 + fq];
      const float* ap = &aggf[d*ASTR + fq*8];
      float o0 = dn*(ap[0] + lo16f(sv.x));
      float o1 = dn*(ap[1] + hi16f(sv.x));
      float o2 = dn*(ap[2] + lo16f(sv.y));
      float o3 = dn*(ap[3] + hi16f(sv.y));
      float o4 = dn*(ap[4] + lo16f(sv.z));
      float o5 = dn*(ap[5] + hi16f(sv.z));
      float o6 = dn*(ap[6] + lo16f(sv.w));
      float o7 = dn*(ap[7] + hi16f(sv.w));
      uint4 pk;
      pk.x = (unsigned)f2b(o0) | ((unsigned)f2b(o1) << 16);
      pk.y = (unsigned)f2b(o2) | ((unsigned)f2b(o3) << 16);
      pk.z = (unsigned)f2b(o4) | ((unsigned)f2b(o5) << 16);
      pk.w = (unsigned)f2b(o6) | ((unsigned)f2b(o7) << 16);
      agg4[(size_t)n*4 + fq] = pk;
    }
  }
}

// ---------------- ALL GRU steps v2: h in registers, rcp gates, direct A loads ---
__global__ __launch_bounds__(256) void gates_kernel(const ushort_t* __restrict__ aggb,
                                                    const float* __restrict__ wbias,
                                                    const short* __restrict__ wfrag,
                                                    float* __restrict__ out){
  __shared__ __align__(16) short Hsp[4096];   // 64 x 64  (8 KB) swizzled
  __shared__ __align__(16) short HRp[4096];   // 64 x 64  (8 KB) swizzled
  int tid = threadIdx.x;
  int nb = blockIdx.x*64;
  int wv = tid >> 6, lane = tid & 63;
  int q = lane >> 4, l15 = lane & 15;
  #pragma unroll
  for (int r = 0; r < 8; r++) ((int*)Hsp)[tid + 256*r] = 0;
  short8 wz[3], wr[3], wh[3];
  #pragma unroll
  for (int kc = 0; kc < 3; kc++){
    wz[kc] = ((const short8*)wfrag)[(wv*3 + kc)*64 + lane];
    wr[kc] = ((const short8*)wfrag)[((wv+4)*3 + kc)*64 + lane];
    wh[kc] = ((const short8*)wfrag)[(24 + wv*3 + kc)*64 + lane];
  }
  int jz = wv*16 + l15;
  float cz = wbias[jz], cr = wbias[64 + jz], ch = wbias[128 + jz];
  int c0 = jz >> 3, jl = jz & 7, x0 = c0 & 7;
  int sq0 = q & 7, sq1 = (4 + q) & 7;         // swizzle keys for chunk q / 4+q
  float hreg[4][4];
  #pragma unroll
  for (int mt = 0; mt < 4; mt++)
    #pragma unroll
    for (int e = 0; e < 4; e++) hreg[mt][e] = 0.f;
  f32x4 accZ[4], accH[4];
  const short8* agf = (const short8*)aggb;
  for (int t = 0; t < TT; t++){
    // direct global A-fragment loads (issued before barrier; tile is L1-hot)
    short8 fac[4];
    #pragma unroll
    for (int mt = 0; mt < 4; mt++){
      int gn = nb + mt*16 + l15;
      short8 v = {0,0,0,0,0,0,0,0};
      if (gn < NN) v = agf[((size_t)t*NN + gn)*4 + q];
      fac[mt] = v;
    }
    __syncthreads();   // prev-iter Hsp writes visible
    #pragma unroll
    for (int mt = 0; mt < 4; mt++){
      int n = mt*16 + l15;
      short8 fh0 = *(const short8*)&Hsp[((q)*64   + (n ^ sq0))*8];
      short8 fh1 = *(const short8*)&Hsp[((4+q)*64 + (n ^ sq1))*8];
      f32x4 az = {0.f,0.f,0.f,0.f}, ar = {0.f,0.f,0.f,0.f};
      az = __builtin_amdgcn_mfma_f32_16x16x32_bf16(fac[mt], wz[0], az, 0,0,0);
      az = __builtin_amdgcn_mfma_f32_16x16x32_bf16(fh0,     wz[1], az, 0,0,0);
      az = __builtin_amdgcn_mfma_f32_16x16x32_bf16(fh1,     wz[2], az, 0,0,0);
      ar = __builtin_amdgcn_mfma_f32_16x16x32_bf16(fac[mt], wr[0], ar, 0,0,0);
      ar = __builtin_amdgcn_mfma_f32_16x16x32_bf16(fh0,     wr[1], ar, 0,0,0);
      ar = __builtin_amdgcn_mfma_f32_16x16x32_bf16(fh1,     wr[2], ar, 0,0,0);
      accZ[mt] = az; accH[mt] = ar;
    }
    #pragma unroll
    for (int mt = 0; mt < 4; mt++){
      #pragma unroll
      for (int e = 0; e < 4; e++){
        int node = mt*16 + q*4 + e;
        float z = __builtin_amdgcn_rcpf(1.f + __expf(-(accZ[mt][e] + cz)));
        float r = __builtin_amdgcn_rcpf(1.f + __expf(-(accH[mt][e] + cr)));
        HRp[(c0*64 + (node ^ x0))*8 + jl] = (short)f2b(hreg[mt][e] * r);
        accZ[mt][e] = z;
      }
    }
    __syncthreads();   // HRp complete
    #pragma unroll
    for (int mt = 0; mt < 4; mt++){
      int n = mt*16 + l15;
      short8 fr0 = *(const short8*)&HRp[((q)*64   + (n ^ sq0))*8];
      short8 fr1 = *(const short8*)&HRp[((4+q)*64 + (n ^ sq1))*8];
      f32x4 ahh = {0.f,0.f,0.f,0.f};
      ahh = __builtin_amdgcn_mfma_f32_16x16x32_bf16(fac[mt], wh[0], ahh, 0,0,0);
      ahh = __builtin_amdgcn_mfma_f32_16x16x32_bf16(fr0,     wh[1], ahh, 0,0,0);
      ahh = __builtin_amdgcn_mfma_f32_16x16x32_bf16(fr1,     wh[2], ahh, 0,0,0);
      accH[mt] = ahh;
    }
    #pragma unroll
    for (int mt = 0; mt < 4; mt++){
      #pragma unroll
      for (int e = 0; e < 4; e++){
        int node = mt*16 + q*4 + e;
        float xv = accH[mt][e] + ch;
        float ex = __expf(-2.f*fabsf(xv));
        float th = (1.f - ex) * __builtin_amdgcn_rcpf(1.f + ex);
        th = (xv < 0.f) ? -th : th;
        float z = accZ[mt][e];
        float hv = z*hreg[mt][e] + (1.f - z)*th;
        hreg[mt][e] = hv;
        Hsp[(c0*64 + (node ^ x0))*8 + jl] = (short)f2b(hv);
      }
    }
  }
  __syncthreads();
  short8 wo0 = ((const short8*)wfrag)[36*64 + lane];
  short8 wo1 = ((const short8*)wfrag)[37*64 + lane];
  int no = wv*16 + l15;
  short8 f0 = *(const short8*)&Hsp[((q)*64   + (no ^ sq0))*8];
  short8 f1 = *(const short8*)&Hsp[((4+q)*64 + (no ^ sq1))*8];
  f32x4 ao = {0.f,0.f,0.f,0.f};
  ao = __builtin_amdgcn_mfma_f32_16x16x32_bf16(f0, wo0, ao, 0,0,0);
  ao = __builtin_amdgcn_mfma_f32_16x16x32_bf16(f1, wo1, ao, 0,0,0);
  float ob = wbias[192 + l15];
  #pragma unroll
  for (int e = 0; e < 4; e++){
    int gn = nb + wv*16 + q*4 + e;
    if (gn < NN) out[gn*OO + l15] = ao[e] + ob;
  }
}

extern "C" void kernel_launch(void* const* d_in, const int* in_sizes, int n_in,
                              void* d_out, int out_size, void* d_ws, size_t ws_size,
                              hipStream_t stream) {
  const float* xs = (const float*)d_in[0];
  const int*   ei = (const int*)d_in[1];
  float* out = (float*)d_out;
  char* ws = (char*)d_ws;
  // workspace layout (bytes); total ~58.5 MB
  ushort_t*  aggb   = (ushort_t*)(ws + 0);           // 19,200,000
  ushort_t*  xbs    = (ushort_t*)(ws + 19200000);    // 19,200,000 (pre-scaled bf16)
  ushort_t*  ssrc16 = (ushort_t*)(ws + 38400000);    // 12,582,912
  uchar_t*   sdst8  = (uchar_t*) (ws + 50982912);    //  6,291,456
  float*     dinv   = (float*)   (ws + 57274368);    //  1,200,000
  int*       bcur   = (int*)     (ws + 58474368);    //  6,144
  short*     wfrag  = (short*)   (ws + 58480512);    //  38,912
  float*     wbias  = (float*)   (ws + 58519424);    //  832 -> end 58,520,256

  prepall_kernel<<<77, 256, 0, stream>>>(
      (const float*)d_in[2],(const float*)d_in[3],(const float*)d_in[4],(const float*)d_in[5],
      (const float*)d_in[6],(const float*)d_in[7],(const float*)d_in[8],(const float*)d_in[9],
      (const float*)d_in[10],(const float*)d_in[11],(const float*)d_in[12],(const float*)d_in[13],
      (const float*)d_in[14],(const float*)d_in[15], wfrag, wbias, bcur);
  scatter_kernel<<<dim3((EE + CHUNK-1)/CHUNK, TT), 256, 0, stream>>>(ei, bcur, ssrc16, sdst8);
  degdinv_kernel<<<dim3(NB, TT), 256, 0, stream>>>(sdst8, bcur, dinv);
  cvtscale_kernel<<<(TT*NN*8 + 255)/256, 256, 0, stream>>>((const float4*)xs, dinv, (ushort4*)xbs);
  gatherb_kernel<<<NB*TT, 256, 0, stream>>>(xbs, ssrc16, sdst8, bcur, dinv, aggb);
  gates_kernel<<<(NN + 63)/64, 256, 0, stream>>>(aggb, wbias, wfrag, out);
}

// Round 6
// 239.321 us; speedup vs baseline: 4.1876x; 4.1876x over previous
//
#include <hip/hip_runtime.h>
#include <hip/hip_bf16.h>

#define TT 6
#define NN 50000
#define EE 800000
#define FF 32
#define HH 64
#define OO 16

#define NB 256        // dst buckets
#define DPB 196       // dsts per bucket (256*196 = 50176 >= 50000)
#define CHUNK 4096    // edges per block in scatter
#define CAP 4096      // slab capacity per (t,bucket): mean 3125, sd 56 -> 17 sigma

#define WFRAG_N 19456  // 38 slots * 512 bf16 fragment-packed weights
// wbias layout: [0..63] cz, [64..127] cr, [128..191] ch, [192..207] out_b

typedef unsigned short ushort_t;
typedef unsigned char uchar_t;
typedef short short8 __attribute__((ext_vector_type(8)));   // 8 bf16 (4 VGPRs)
typedef float f32x4 __attribute__((ext_vector_type(4)));

__device__ __forceinline__ float ubf(ushort_t v){ return __uint_as_float(((unsigned)v) << 16); }
__device__ __forceinline__ ushort_t f2b(float f){
  unsigned u = __float_as_uint(f);
  return (ushort_t)((u + 0x7FFFu + ((u >> 16) & 1u)) >> 16);
}
__device__ __forceinline__ float lo16f(unsigned u){ return __uint_as_float(u << 16); }
__device__ __forceinline__ float hi16f(unsigned u){ return __uint_as_float(u & 0xFFFF0000u); }

// LESSON (v7/v8 post-mortem): LDS *float* atomics on gfx950 are lane-serialized
// (~3 cyc/lane-atomic/CU; 820us for 153M of them, VALUBusy 2%). Never use f32
// LDS atomics in bulk. Int LDS atomics are fine (used below).

// ---------------- fused prep: wfrag (direct from raw weights) + biases + bcur zero
__global__ void prepall_kernel(const float* __restrict__ Wz,const float* __restrict__ bz,
                               const float* __restrict__ Wr,const float* __restrict__ br,
                               const float* __restrict__ Wh,const float* __restrict__ bh,
                               const float* __restrict__ Lz,const float* __restrict__ Lzb,
                               const float* __restrict__ Lr,const float* __restrict__ Lrb,
                               const float* __restrict__ Lh,const float* __restrict__ Lhb,
                               const float* __restrict__ oW,const float* __restrict__ ob,
                               short* __restrict__ wfrag, float* __restrict__ wbias,
                               int* __restrict__ bcur){
  int bid = blockIdx.x, tid = threadIdx.x;
  if (bid < 76){
    int idx = bid*256 + tid;   // 0..19455
    int slot = idx >> 9, lane = (idx >> 3) & 63, j = idx & 7;
    int q = lane >> 4, l15 = lane & 15;
    float val;
    if (slot < 36){
      int g, kc, ncol;
      if (slot < 24){ int nt = slot/3; kc = slot - nt*3; ncol = nt*16 + l15;
                      g = (ncol < 64) ? 0 : 1; ncol &= 63; }
      else          { int s2 = slot-24; int nt = s2/3; kc = s2 - nt*3;
                      ncol = nt*16 + l15; g = 2; }
      const float* W = (g==0)?Wz:((g==1)?Wr:Wh);     // [32][64]
      const float* L = (g==0)?Lz:((g==1)?Lr:Lh);     // [128][64]
      int k = kc*32 + q*8 + j;                        // 0..95
      if (k < 32){                                    // fused W@L[:64]
        float s = 0.f;
        for (int m = 0; m < 64; m++) s += W[k*64+m] * L[m*64+ncol];
        val = s;
      } else val = L[(32+k)*64 + ncol];               // L rows 64..127
    } else {
      int kc = slot - 36;
      int k = kc*32 + q*8 + j;                        // 0..63
      val = oW[k*16 + l15];
    }
    wfrag[idx] = (short)f2b(val);
  } else {
    if (tid < 192){
      int g = tid >> 6, j = tid & 63;
      const float* L  = (g==0)?Lz:((g==1)?Lr:Lh);
      const float* bb = (g==0)?bz:((g==1)?br:bh);
      const float* Lb = (g==0)?Lzb:((g==1)?Lrb:Lhb);
      float s = Lb[j];
      for (int m = 0; m < 64; m++) s += bb[m] * L[m*64+j];
      wbias[tid] = s;
    } else if (tid < 208){
      wbias[tid] = ob[tid-192];
    }
    for (int i = tid; i < 1536; i += 256) bcur[i] = 0;
  }
}

// ---------------- scatter: LDS counting-sort by bucket -> coalesced slab writes --
__global__ __launch_bounds__(256) void scatter_kernel(const int* __restrict__ ei,
                                                      int* __restrict__ bcur,
                                                      ushort_t* __restrict__ ssrc16,
                                                      uchar_t* __restrict__ sdst8){
  int t = blockIdx.y;
  __shared__ int cnt[NB];
  __shared__ int lstart[NB];
  __shared__ int gbase[NB];
  __shared__ int wsum[4];
  __shared__ ushort_t spay[CHUNK];
  __shared__ uchar_t  sdlo[CHUNK];
  __shared__ uchar_t  sbk[CHUNK];
  int tid = threadIdx.x;
  cnt[tid] = 0;
  __syncthreads();
  int e0 = blockIdx.x*CHUNK;
  const int* srcs = ei + t*2*EE;
  const int* dsts = ei + t*2*EE + EE;
  int pk[CHUNK/256];
  int ps[CHUNK/256];
  int pd[CHUNK/256];
  #pragma unroll
  for (int i = 0; i < CHUNK/256; i++){
    int e = e0 + i*256 + tid;
    if (e < EE){
      int s = srcs[e], d = dsts[e];
      int b = d / DPB;
      int lr = atomicAdd(&cnt[b], 1);
      pk[i] = (b << 12) | lr;
      ps[i] = s;
      pd[i] = d - b*DPB;
    } else pk[i] = -1;
  }
  __syncthreads();
  {
    int v = cnt[tid];
    int lane = tid & 63, wid = tid >> 6;
    int x = v;
    #pragma unroll
    for (int o = 1; o < 64; o <<= 1){
      int y = __shfl_up(x, o, 64);
      if (lane >= o) x += y;
    }
    if (lane == 63) wsum[wid] = x;
    __syncthreads();
    if (tid == 0){
      int s = 0;
      #pragma unroll
      for (int w = 0; w < 4; w++){ int tmp = wsum[w]; wsum[w] = s; s += tmp; }
    }
    __syncthreads();
    lstart[tid] = x - v + wsum[wid];
    gbase[tid] = (v > 0) ? atomicAdd(&bcur[t*NB + tid], v) : 0;
  }
  __syncthreads();
  #pragma unroll
  for (int i = 0; i < CHUNK/256; i++){
    if (pk[i] >= 0){
      int b = pk[i] >> 12, lr = pk[i] & 4095;
      int pos = lstart[b] + lr;
      spay[pos] = (ushort_t)ps[i];
      sdlo[pos] = (uchar_t)pd[i];
      sbk[pos]  = (uchar_t)b;
    }
  }
  __syncthreads();
  int nE = EE - e0; if (nE > CHUNK) nE = CHUNK;
  for (int i = tid; i < nE; i += 256){
    int b = sbk[i];
    int gpos = gbase[b] + (i - lstart[b]);
    if (gpos < CAP){
      size_t sb = (size_t)(t*NB + b)*CAP + gpos;
      ssrc16[sb] = spay[i];
      sdst8[sb]  = sdlo[i];
    }
  }
}

// ---------------- per-bucket degree -> dinv + per-dst exclusive offsets --------
// Extended: the histogram it already builds is exactly what gatherb's sort needs,
// so scan it here (shfl, 2 barriers) and publish soffg[(t*NB+b)*197 + 0..196].
__global__ __launch_bounds__(256) void degdinv_kernel(const uchar_t* __restrict__ sdst8,
                                                      const int* __restrict__ bcur,
                                                      float* __restrict__ dinv,
                                                      int* __restrict__ soffg){
  int b = blockIdx.x, t = blockIdx.y, tid = threadIdx.x;
  __shared__ int cnt[DPB];
  __shared__ int wsum[4];
  for (int i = tid; i < DPB; i += 256) cnt[i] = 0;
  __syncthreads();
  int ecnt = bcur[t*NB + b]; if (ecnt > CAP) ecnt = CAP;
  const uchar_t* dp = sdst8 + (size_t)(t*NB + b)*CAP;
  for (int i = tid; i < ecnt; i += 256)
    atomicAdd(&cnt[dp[i]], 1);
  __syncthreads();
  int v = (tid < DPB) ? cnt[tid] : 0;
  {
    int lane = tid & 63, wid = tid >> 6;
    int x = v;
    #pragma unroll
    for (int o = 1; o < 64; o <<= 1){
      int y = __shfl_up(x, o, 64);
      if (lane >= o) x += y;
    }
    if (lane == 63) wsum[wid] = x;
    __syncthreads();
    if (tid == 0){
      int s = 0;
      #pragma unroll
      for (int w = 0; w < 4; w++){ int tmp = wsum[w]; wsum[w] = s; s += tmp; }
    }
    __syncthreads();
    int excl = x - v + wsum[wid];
    if (tid <= DPB) soffg[(size_t)(t*NB + b)*(DPB+1) + tid] = excl;
  }
  for (int i = tid; i < DPB; i += 256){
    int n = b*DPB + i;
    if (n < NN) dinv[t*NN + n] = rsqrtf((float)(cnt[i] + 1));  // +1 self loop
  }
}

// ---------------- convert + pre-scale: xbs[t][n][f] = bf16(dinv[t][n] * x[t][n][f])
__global__ void cvtscale_kernel(const float4* __restrict__ x4,
                                const float* __restrict__ dinv,
                                ushort4* __restrict__ xb4){
  int i = blockIdx.x*256 + threadIdx.x;     // float4 index, 2,400,000 total
  if (i < TT*NN*8){
    float dn = dinv[i >> 3];
    float4 v = x4[i];
    ushort4 o;
    o.x = f2b(v.x*dn); o.y = f2b(v.y*dn); o.z = f2b(v.z*dn); o.w = f2b(v.w*dn);
    xb4[i] = o;
  }
}

// ---------------- bucket gather v9: v6 reduce + precomputed soff + work stealing
// vs v6 (51.9us): (a) histogram+scan removed -- soff comes precomputed from
// degdinv (one LDS-int-atomic pass instead of two); (b) reduce phase claims dsts
// dynamically from a shared cursor (196 int-atomic claims/block) so the 32
// 8-lane groups drain a common pool: per-wave iterations ~= mean, not
// max-over-8-Poisson-chains (~1.6x straggler waste in v6). Inner unroll-8 loop
// and epilogue are verbatim v6.
__global__ __launch_bounds__(256) void gatherb_kernel(const ushort_t* __restrict__ xbs,
                                                      const ushort_t* __restrict__ ssrc16,
                                                      const uchar_t* __restrict__ sdst8,
                                                      const int* __restrict__ bcur,
                                                      const int* __restrict__ soffg,
                                                      ushort_t* __restrict__ aggb){
  int l = blockIdx.x;
  int wk = ((l & 7) * 192) + (l >> 3);
  int t = wk >> 8;
  int b = wk & 255;
  int tid = threadIdx.x;
  __shared__ ushort_t ssrc[CAP];      // 8 KB dst-sorted srcs
  __shared__ int scnt[DPB];           // rank cursor
  __shared__ int soff[DPB + 1];
  __shared__ int dcur;                // dynamic dst claim cursor
  int ecnt = bcur[t*NB + b]; if (ecnt > CAP) ecnt = CAP;
  size_t slab = (size_t)(t*NB + b)*CAP;
  const ushort_t* sp = ssrc16 + slab;
  const uchar_t*  dp = sdst8 + slab;
  const int* sg = soffg + (size_t)(t*NB + b)*(DPB+1);
  if (tid <= DPB){
    int v = sg[tid];
    soff[tid] = v;
    if (tid < DPB) scnt[tid] = v;
  }
  if (tid == 0) dcur = 0;
  __syncthreads();
  // rank & place (single pass over slab; pos < ecnt <= CAP by construction)
  for (int e = tid; e < ecnt; e += 256){
    int d = dp[e];
    int pos = atomicAdd(&scnt[d], 1);
    ssrc[pos] = sp[e];
  }
  __syncthreads();
  // reduce: 8-lane group claims one dst at a time from the shared pool
  int lane = tid & 63;
  int fp = lane & 7;
  const uint2* xb2 = (const uint2*)xbs + (size_t)t*NN*8;
  uint2* agg2 = (uint2*)aggb + (size_t)t*NN*8;
  while (true){
    int ld = 0;
    if ((lane & 7) == 0) ld = atomicAdd(&dcur, 1);
    ld = __shfl(ld, lane & 56, 64);
    if (ld >= DPB) break;
    int e0 = soff[ld], e1 = soff[ld + 1];
    float a0 = 0.f, a1 = 0.f, a2 = 0.f, a3 = 0.f;
    for (int i = e0; i < e1; i += 8){
      int sidx[8];
      uint2 rr[8];
      #pragma unroll
      for (int k = 0; k < 8; k++){
        int ik = i + k;
        sidx[k] = (int)ssrc[(ik < e1) ? ik : (e1 - 1)];
      }
      #pragma unroll
      for (int k = 0; k < 8; k++)
        rr[k] = xb2[(size_t)sidx[k]*8 + fp];
      #pragma unroll
      for (int k = 0; k < 8; k++){
        if (i + k >= e1){ rr[k].x = 0u; rr[k].y = 0u; }
        a0 += lo16f(rr[k].x); a1 += hi16f(rr[k].x);
        a2 += lo16f(rr[k].y); a3 += hi16f(rr[k].y);
      }
    }
    int n = b*DPB + ld;
    if (n < NN){
      float dn = rsqrtf((float)(e1 - e0 + 1));  // local degree -> dinv
      uint2 sv = xb2[(size_t)n*8 + fp];         // self term (pre-scaled row)
      float o0 = dn*(a0 + lo16f(sv.x));
      float o1 = dn*(a1 + hi16f(sv.x));
      float o2 = dn*(a2 + lo16f(sv.y));
      float o3 = dn*(a3 + hi16f(sv.y));
      uint2 pk;
      pk.x = (unsigned)f2b(o0) | ((unsigned)f2b(o1) << 16);
      pk.y = (unsigned)f2b(o2) | ((unsigned)f2b(o3) << 16);
      agg2[(size_t)n*8 + fp] = pk;
    }
  }
}

// ---------------- ALL GRU steps v2: h in registers, rcp gates, direct A loads ---
__global__ __launch_bounds__(256) void gates_kernel(const ushort_t* __restrict__ aggb,
                                                    const float* __restrict__ wbias,
                                                    const short* __restrict__ wfrag,
                                                    float* __restrict__ out){
  __shared__ __align__(16) short Hsp[4096];   // 64 x 64  (8 KB) swizzled
  __shared__ __align__(16) short HRp[4096];   // 64 x 64  (8 KB) swizzled
  int tid = threadIdx.x;
  int nb = blockIdx.x*64;
  int wv = tid >> 6, lane = tid & 63;
  int q = lane >> 4, l15 = lane & 15;
  #pragma unroll
  for (int r = 0; r < 8; r++) ((int*)Hsp)[tid + 256*r] = 0;
  short8 wz[3], wr[3], wh[3];
  #pragma unroll
  for (int kc = 0; kc < 3; kc++){
    wz[kc] = ((const short8*)wfrag)[(wv*3 + kc)*64 + lane];
    wr[kc] = ((const short8*)wfrag)[((wv+4)*3 + kc)*64 + lane];
    wh[kc] = ((const short8*)wfrag)[(24 + wv*3 + kc)*64 + lane];
  }
  int jz = wv*16 + l15;
  float cz = wbias[jz], cr = wbias[64 + jz], ch = wbias[128 + jz];
  int c0 = jz >> 3, jl = jz & 7, x0 = c0 & 7;
  int sq0 = q & 7, sq1 = (4 + q) & 7;         // swizzle keys for chunk q / 4+q
  float hreg[4][4];
  #pragma unroll
  for (int mt = 0; mt < 4; mt++)
    #pragma unroll
    for (int e = 0; e < 4; e++) hreg[mt][e] = 0.f;
  f32x4 accZ[4], accH[4];
  const short8* agf = (const short8*)aggb;
  for (int t = 0; t < TT; t++){
    // direct global A-fragment loads (issued before barrier; tile is L1-hot)
    short8 fac[4];
    #pragma unroll
    for (int mt = 0; mt < 4; mt++){
      int gn = nb + mt*16 + l15;
      short8 v = {0,0,0,0,0,0,0,0};
      if (gn < NN) v = agf[((size_t)t*NN + gn)*4 + q];
      fac[mt] = v;
    }
    __syncthreads();   // prev-iter Hsp writes visible
    #pragma unroll
    for (int mt = 0; mt < 4; mt++){
      int n = mt*16 + l15;
      short8 fh0 = *(const short8*)&Hsp[((q)*64   + (n ^ sq0))*8];
      short8 fh1 = *(const short8*)&Hsp[((4+q)*64 + (n ^ sq1))*8];
      f32x4 az = {0.f,0.f,0.f,0.f}, ar = {0.f,0.f,0.f,0.f};
      az = __builtin_amdgcn_mfma_f32_16x16x32_bf16(fac[mt], wz[0], az, 0,0,0);
      az = __builtin_amdgcn_mfma_f32_16x16x32_bf16(fh0,     wz[1], az, 0,0,0);
      az = __builtin_amdgcn_mfma_f32_16x16x32_bf16(fh1,     wz[2], az, 0,0,0);
      ar = __builtin_amdgcn_mfma_f32_16x16x32_bf16(fac[mt], wr[0], ar, 0,0,0);
      ar = __builtin_amdgcn_mfma_f32_16x16x32_bf16(fh0,     wr[1], ar, 0,0,0);
      ar = __builtin_amdgcn_mfma_f32_16x16x32_bf16(fh1,     wr[2], ar, 0,0,0);
      accZ[mt] = az; accH[mt] = ar;
    }
    #pragma unroll
    for (int mt = 0; mt < 4; mt++){
      #pragma unroll
      for (int e = 0; e < 4; e++){
        int node = mt*16 + q*4 + e;
        float z = __builtin_amdgcn_rcpf(1.f + __expf(-(accZ[mt][e] + cz)));
        float r = __builtin_amdgcn_rcpf(1.f + __expf(-(accH[mt][e] + cr)));
        HRp[(c0*64 + (node ^ x0))*8 + jl] = (short)f2b(hreg[mt][e] * r);
        accZ[mt][e] = z;
      }
    }
    __syncthreads();   // HRp complete
    #pragma unroll
    for (int mt = 0; mt < 4; mt++){
      int n = mt*16 + l15;
      short8 fr0 = *(const short8*)&HRp[((q)*64   + (n ^ sq0))*8];
      short8 fr1 = *(const short8*)&HRp[((4+q)*64 + (n ^ sq1))*8];
      f32x4 ahh = {0.f,0.f,0.f,0.f};
      ahh = __builtin_amdgcn_mfma_f32_16x16x32_bf16(fac[mt], wh[0], ahh, 0,0,0);
      ahh = __builtin_amdgcn_mfma_f32_16x16x32_bf16(fr0,     wh[1], ahh, 0,0,0);
      ahh = __builtin_amdgcn_mfma_f32_16x16x32_bf16(fr1,     wh[2], ahh, 0,0,0);
      accH[mt] = ahh;
    }
    #pragma unroll
    for (int mt = 0; mt < 4; mt++){
      #pragma unroll
      for (int e = 0; e < 4; e++){
        int node = mt*16 + q*4 + e;
        float xv = accH[mt][e] + ch;
        float ex = __expf(-2.f*fabsf(xv));
        float th = (1.f - ex) * __builtin_amdgcn_rcpf(1.f + ex);
        th = (xv < 0.f) ? -th : th;
        float z = accZ[mt][e];
        float hv = z*hreg[mt][e] + (1.f - z)*th;
        hreg[mt][e] = hv;
        Hsp[(c0*64 + (node ^ x0))*8 + jl] = (short)f2b(hv);
      }
    }
  }
  __syncthreads();
  short8 wo0 = ((const short8*)wfrag)[36*64 + lane];
  short8 wo1 = ((const short8*)wfrag)[37*64 + lane];
  int no = wv*16 + l15;
  short8 f0 = *(const short8*)&Hsp[((q)*64   + (no ^ sq0))*8];
  short8 f1 = *(const short8*)&Hsp[((4+q)*64 + (no ^ sq1))*8];
  f32x4 ao = {0.f,0.f,0.f,0.f};
  ao = __builtin_amdgcn_mfma_f32_16x16x32_bf16(f0, wo0, ao, 0,0,0);
  ao = __builtin_amdgcn_mfma_f32_16x16x32_bf16(f1, wo1, ao, 0,0,0);
  float ob = wbias[192 + l15];
  #pragma unroll
  for (int e = 0; e < 4; e++){
    int gn = nb + wv*16 + q*4 + e;
    if (gn < NN) out[gn*OO + l15] = ao[e] + ob;
  }
}

extern "C" void kernel_launch(void* const* d_in, const int* in_sizes, int n_in,
                              void* d_out, int out_size, void* d_ws, size_t ws_size,
                              hipStream_t stream) {
  const float* xs = (const float*)d_in[0];
  const int*   ei = (const int*)d_in[1];
  float* out = (float*)d_out;
  char* ws = (char*)d_ws;
  // workspace layout (bytes); total ~59.7 MB
  ushort_t*  aggb   = (ushort_t*)(ws + 0);           // 19,200,000
  ushort_t*  xbs    = (ushort_t*)(ws + 19200000);    // 19,200,000 (pre-scaled bf16)
  ushort_t*  ssrc16 = (ushort_t*)(ws + 38400000);    // 12,582,912
  uchar_t*   sdst8  = (uchar_t*) (ws + 50982912);    //  6,291,456
  float*     dinv   = (float*)   (ws + 57274368);    //  1,200,000
  int*       bcur   = (int*)     (ws + 58474368);    //  6,144
  short*     wfrag  = (short*)   (ws + 58480512);    //  38,912
  float*     wbias  = (float*)   (ws + 58519424);    //  832
  int*       soffg  = (int*)     (ws + 58520320);    //  1,210,368 -> end 59,730,688

  prepall_kernel<<<77, 256, 0, stream>>>(
      (const float*)d_in[2],(const float*)d_in[3],(const float*)d_in[4],(const float*)d_in[5],
      (const float*)d_in[6],(const float*)d_in[7],(const float*)d_in[8],(const float*)d_in[9],
      (const float*)d_in[10],(const float*)d_in[11],(const float*)d_in[12],(const float*)d_in[13],
      (const float*)d_in[14],(const float*)d_in[15], wfrag, wbias, bcur);
  scatter_kernel<<<dim3((EE + CHUNK-1)/CHUNK, TT), 256, 0, stream>>>(ei, bcur, ssrc16, sdst8);
  degdinv_kernel<<<dim3(NB, TT), 256, 0, stream>>>(sdst8, bcur, dinv, soffg);
  cvtscale_kernel<<<(TT*NN*8 + 255)/256, 256, 0, stream>>>((const float4*)xs, dinv, (ushort4*)xbs);
  gatherb_kernel<<<NB*TT, 256, 0, stream>>>(xbs, ssrc16, sdst8, bcur, soffg, aggb);
  gates_kernel<<<(NN + 63)/64, 256, 0, stream>>>(aggb, wbias, wfrag, out);
}